// Round 10
// baseline (206.148 us; speedup 1.0000x reference)
//
#include <hip/hip_runtime.h>
#include <hip/hip_bf16.h>
#include <stdint.h>

#define QMAX 127.0f

typedef __attribute__((ext_vector_type(4))) int   i32x4;
typedef __attribute__((ext_vector_type(2))) int   i32x2;
typedef __attribute__((ext_vector_type(4))) float f32x4v;

typedef __attribute__((address_space(1))) const void GVoid;
typedef __attribute__((address_space(3))) void LVoid;

__device__ inline int quant_i(float x, float inv) {
    float q = rintf(x * inv);                 // inv = 127/absmax (one div per row)
    q = fminf(fmaxf(q, -QMAX), QMAX);
    return (int)q;                            // exact: q integral, |q|<=127
}

__device__ inline uint32_t pack4(f32x4v v, float inv) {
    return (uint32_t)(quant_i(v.x, inv) & 255)
         | ((uint32_t)(quant_i(v.y, inv) & 255) << 8)
         | ((uint32_t)(quant_i(v.z, inv) & 255) << 16)
         | ((uint32_t)(quant_i(v.w, inv) & 255) << 24);
}

__device__ inline float amax8(f32x4v a, f32x4v b) {
    return fmaxf(fmaxf(fmaxf(fabsf(a.x), fabsf(a.y)), fmaxf(fabsf(a.z), fabsf(a.w))),
                 fmaxf(fmaxf(fabsf(b.x), fabsf(b.y)), fmaxf(fabsf(b.z), fabsf(b.w))));
}

// ---- kernel 1: fused quantizer (single dispatch) ----
// blocks [0, nLhs): quantize 32 lhs rows each -> int8 Aq + lscale (NT loads: lhs dead after)
// blocks [nLhs, nLhs+128): wave w quantizes rhs column (b-nLhs)*4+w -> Bt int8 [F][K] + rscale
__global__ __launch_bounds__(256, 8) void quant_kernel(const float* __restrict__ lhs,
                                                       const float* __restrict__ rhs,
                                                       int8_t* __restrict__ Aq,
                                                       int8_t* __restrict__ Bt,
                                                       float* __restrict__ lscale,
                                                       float* __restrict__ rscale,
                                                       int nLhs) {
    const int lane = threadIdx.x & 63;
    const int wave = threadIdx.x >> 6;
    const int bid  = blockIdx.x;

    if (bid >= nLhs) {
        // ---- rhs path: one wave per column ----
        const int f = (bid - nLhs) * 4 + wave;
        float v[8];
        float amax = 0.f;
#pragma unroll
        for (int i = 0; i < 8; ++i) {
            v[i] = rhs[(size_t)(lane + 64 * i) * 512 + f];
            amax = fmaxf(amax, fabsf(v[i]));
        }
#pragma unroll
        for (int m = 1; m <= 32; m <<= 1)
            amax = fmaxf(amax, __shfl_xor(amax, m, 64));
        const float inv = amax > 0.f ? QMAX / amax : 0.f;
        if (lane == 0) rscale[f] = amax > 0.f ? amax * (1.0f / QMAX) : 1.0f;
#pragma unroll
        for (int i = 0; i < 8; ++i)
            Bt[(size_t)f * 512 + lane + 64 * i] = (int8_t)quant_i(v[i], inv);
        return;
    }

    // ---- lhs path: this wave owns 8 rows ----
    const int row0 = bid * 32 + wave * 8;
    const float* rp = lhs + (size_t)row0 * 512 + lane * 8;
    int8_t* op = Aq + (size_t)row0 * 512 + lane * 8;
#pragma unroll
    for (int r = 0; r < 8; r += 2) {
        const f32x4v a0 = __builtin_nontemporal_load((const f32x4v*)(rp + (size_t)r * 512));
        const f32x4v b0 = __builtin_nontemporal_load((const f32x4v*)(rp + (size_t)r * 512 + 4));
        const f32x4v a1 = __builtin_nontemporal_load((const f32x4v*)(rp + (size_t)(r + 1) * 512));
        const f32x4v b1 = __builtin_nontemporal_load((const f32x4v*)(rp + (size_t)(r + 1) * 512 + 4));
        float m0 = amax8(a0, b0);
        float m1 = amax8(a1, b1);
#pragma unroll
        for (int m = 1; m <= 32; m <<= 1) {        // interleaved dual reduce
            m0 = fmaxf(m0, __shfl_xor(m0, m, 64));
            m1 = fmaxf(m1, __shfl_xor(m1, m, 64));
        }
        const float inv0 = m0 > 0.f ? QMAX / m0 : 0.f;
        const float inv1 = m1 > 0.f ? QMAX / m1 : 0.f;
        if (lane == 0) {
            lscale[row0 + r]     = m0 > 0.f ? m0 * (1.0f / QMAX) : 1.0f;
            lscale[row0 + r + 1] = m1 > 0.f ? m1 * (1.0f / QMAX) : 1.0f;
        }
        i32x2 p0, p1;
        p0.x = (int)pack4(a0, inv0); p0.y = (int)pack4(b0, inv0);
        p1.x = (int)pack4(a1, inv1); p1.y = (int)pack4(b1, inv1);
        *(i32x2*)(op + (size_t)r * 512)       = p0;   // normal store: Aq wants L3 residency
        *(i32x2*)(op + (size_t)(r + 1) * 512) = p1;
    }
}

// ---- kernel 2: int8 GEMM, 256x128 tile, BK=128, 512 threads (8 waves 4x2),
// single-buffer 48KB LDS -> 3 blocks/CU = 24 waves/CU (75% occupancy).
// Same proven m97 skeleton; cross-block overlap (m114) hides the barrier drain.
// XCD-aware swizzle: 4 n-tiles of each m-slab on one XCD (A re-reads hit L2).
// LDS XOR-swizzle via pre-swizzled GLOBAL source (m173; gload_lds dest linear).
__global__ __launch_bounds__(512, 6) void gemm_kernel(const int8_t* __restrict__ Aq,
                                                      const int8_t* __restrict__ Bt,
                                                      const float* __restrict__ lscale,
                                                      const float* __restrict__ rscale,
                                                      float* __restrict__ out) {
    __shared__ int8_t lds[49152];  // A [256][128] @0, B^T [128][128] @32768 (both swizzled)

    const int tid  = threadIdx.x;
    const int lane = tid & 63;
    const int wave = tid >> 6;      // 0..7
    const int wr   = wave >> 1;     // 0..3  (64-row band)
    const int wc   = wave & 1;      // 0..1  (64-col band)

    // 1024 blocks = 8 XCDs x 128; slab = xcd*32 + j/4, nc = j%4  (bijective)
    const int g   = blockIdx.x;
    const int xcd = g & 7;
    const int j   = g >> 3;
    const int m0  = (xcd * 32 + (j >> 2)) * 256;
    const int n0  = (j & 3) * 128;

    i32x4 acc[4][4];
#pragma unroll
    for (int i = 0; i < 4; ++i)
#pragma unroll
        for (int jj = 0; jj < 4; ++jj)
            acc[i][jj] = (i32x4){0, 0, 0, 0};

    const int lane15 = lane & 15;
    const int laneHi = lane >> 4;

#pragma unroll
    for (int kt = 0; kt < 512; kt += 128) {
        __syncthreads();   // previous step's frags consumed
        // stage A 32KB: 4 wave-uniform 1KB chunks per wave
#pragma unroll
        for (int c = 0; c < 4; ++c) {
            const int chunk = (c * 8 + wave) * 1024;
            const int d     = chunk + lane * 16;       // linear LDS dest byte
            const int row   = d >> 7;                  // A tile row 0..255
            const int srck  = (d & 127) ^ ((row & 7) << 4);
            const int8_t* srcA = Aq + (size_t)(m0 + row) * 512 + kt + srck;
            __builtin_amdgcn_global_load_lds((GVoid*)srcA, (LVoid*)(lds + chunk), 16, 0, 0);
        }
        // stage B 16KB: 2 chunks per wave
#pragma unroll
        for (int c = 0; c < 2; ++c) {
            const int chunk = (c * 8 + wave) * 1024;
            const int d     = chunk + lane * 16;
            const int row   = d >> 7;                  // B tile col 0..127
            const int srck  = (d & 127) ^ ((row & 7) << 4);
            const int8_t* srcB = Bt + (size_t)(n0 + row) * 512 + kt + srck;
            __builtin_amdgcn_global_load_lds((GVoid*)srcB, (LVoid*)(lds + 32768 + chunk), 16, 0, 0);
        }
        __syncthreads();   // staging complete (compiler drains vmcnt at barrier)

        i32x4 af[4][2], bf[4][2];
#pragma unroll
        for (int mi = 0; mi < 4; ++mi) {
            const int row = wr * 64 + mi * 16 + lane15;
            const int sw  = (row & 7) << 4;
#pragma unroll
            for (int kk = 0; kk < 2; ++kk) {
                const int kb = kk * 64 + laneHi * 16;
                af[mi][kk] = *(const i32x4*)(lds + row * 128 + (kb ^ sw));
            }
        }
#pragma unroll
        for (int ni = 0; ni < 4; ++ni) {
            const int col = wc * 64 + ni * 16 + lane15;
            const int sw  = (col & 7) << 4;
#pragma unroll
            for (int kk = 0; kk < 2; ++kk) {
                const int kb = kk * 64 + laneHi * 16;
                bf[ni][kk] = *(const i32x4*)(lds + 32768 + col * 128 + (kb ^ sw));
            }
        }
#pragma unroll
        for (int kk = 0; kk < 2; ++kk)
#pragma unroll
            for (int mi = 0; mi < 4; ++mi)
#pragma unroll
                for (int ni = 0; ni < 4; ++ni)
                    acc[mi][ni] = __builtin_amdgcn_mfma_i32_16x16x64_i8(
                        af[mi][kk], bf[ni][kk], acc[mi][ni], 0, 0, 0);
    }

    // ---- epilogue: C/D layout col=lane&15, row=(lane>>4)*4+reg ----
    float rs[4];
#pragma unroll
    for (int ni = 0; ni < 4; ++ni)
        rs[ni] = rscale[n0 + wc * 64 + ni * 16 + lane15];
    const int rg = laneHi * 4;
#pragma unroll
    for (int mi = 0; mi < 4; ++mi) {
#pragma unroll
        for (int r = 0; r < 4; ++r) {
            const int grow = m0 + wr * 64 + mi * 16 + rg + r;
            const float ls = lscale[grow];
            float* op = out + (size_t)grow * 512 + n0 + wc * 64;
#pragma unroll
            for (int ni = 0; ni < 4; ++ni)
                op[ni * 16 + lane15] = (float)acc[mi][ni][r] * ls * rs[ni];
        }
    }
}

extern "C" void kernel_launch(void* const* d_in, const int* in_sizes, int n_in,
                              void* d_out, int out_size, void* d_ws, size_t ws_size,
                              hipStream_t stream) {
    const float* lhs = (const float*)d_in[0];   // [4,16384,512] f32
    const float* rhs = (const float*)d_in[1];   // [512,512] f32
    float* out = (float*)d_out;                 // [4,16384,512] f32

    // ws: Bt i8 [512][512] (256KB) | rscale f32[512] | lscale f32[65536] | Aq i8 [65536][512] (32MB)
    char* ws = (char*)d_ws;
    int8_t* Bt    = (int8_t*)ws;
    float* rscale = (float*)(ws + 262144);
    float* lscale = (float*)(ws + 266240);
    int8_t* Aq    = (int8_t*)(ws + 1048576);

    const int rows = in_sizes[0] / 512;         // 65536
    const int nLhs = rows / 32;                 // 2048

    quant_kernel<<<nLhs + 128, 256, 0, stream>>>(lhs, rhs, Aq, Bt, lscale, rscale, nLhs);
    gemm_kernel<<<(rows / 256) * 4, 512, 0, stream>>>(Aq, Bt, lscale, rscale, out);
}

// Round 11
// 85.720 us; speedup vs baseline: 2.4049x; 2.4049x over previous
//
#include <hip/hip_runtime.h>
#include <hip/hip_bf16.h>
#include <stdint.h>

#define QMAX 127.0f

typedef __attribute__((ext_vector_type(4))) int   i32x4;
typedef __attribute__((ext_vector_type(2))) int   i32x2;
typedef __attribute__((ext_vector_type(4))) float f32x4v;

typedef __attribute__((address_space(1))) const void GVoid;
typedef __attribute__((address_space(3))) void LVoid;

__device__ inline int quant_i(float x, float inv) {
    float q = rintf(x * inv);                 // inv = 127/absmax (one div per row)
    q = fminf(fmaxf(q, -QMAX), QMAX);
    return (int)q;                            // exact: q integral, |q|<=127
}

__device__ inline uint32_t pack4(f32x4v v, float inv) {
    return (uint32_t)(quant_i(v.x, inv) & 255)
         | ((uint32_t)(quant_i(v.y, inv) & 255) << 8)
         | ((uint32_t)(quant_i(v.z, inv) & 255) << 16)
         | ((uint32_t)(quant_i(v.w, inv) & 255) << 24);
}

__device__ inline float amax8(f32x4v a, f32x4v b) {
    return fmaxf(fmaxf(fmaxf(fabsf(a.x), fabsf(a.y)), fmaxf(fabsf(a.z), fabsf(a.w))),
                 fmaxf(fmaxf(fabsf(b.x), fabsf(b.y)), fmaxf(fabsf(b.z), fabsf(b.w))));
}

// ---- kernel 1: fused quantizer (single dispatch) ----
// blocks [0, nLhs): quantize 32 lhs rows each -> int8 Aq + lscale (NT loads: lhs dead after)
// blocks [nLhs, nLhs+128): wave w quantizes rhs column (b-nLhs)*4+w -> Bt int8 [F][K] + rscale
__global__ __launch_bounds__(256, 8) void quant_kernel(const float* __restrict__ lhs,
                                                       const float* __restrict__ rhs,
                                                       int8_t* __restrict__ Aq,
                                                       int8_t* __restrict__ Bt,
                                                       float* __restrict__ lscale,
                                                       float* __restrict__ rscale,
                                                       int nLhs) {
    const int lane = threadIdx.x & 63;
    const int wave = threadIdx.x >> 6;
    const int bid  = blockIdx.x;

    if (bid >= nLhs) {
        // ---- rhs path: one wave per column ----
        const int f = (bid - nLhs) * 4 + wave;
        float v[8];
        float amax = 0.f;
#pragma unroll
        for (int i = 0; i < 8; ++i) {
            v[i] = rhs[(size_t)(lane + 64 * i) * 512 + f];
            amax = fmaxf(amax, fabsf(v[i]));
        }
#pragma unroll
        for (int m = 1; m <= 32; m <<= 1)
            amax = fmaxf(amax, __shfl_xor(amax, m, 64));
        const float inv = amax > 0.f ? QMAX / amax : 0.f;
        if (lane == 0) rscale[f] = amax > 0.f ? amax * (1.0f / QMAX) : 1.0f;
#pragma unroll
        for (int i = 0; i < 8; ++i)
            Bt[(size_t)f * 512 + lane + 64 * i] = (int8_t)quant_i(v[i], inv);
        return;
    }

    // ---- lhs path: this wave owns 8 rows ----
    const int row0 = bid * 32 + wave * 8;
    const float* rp = lhs + (size_t)row0 * 512 + lane * 8;
    int8_t* op = Aq + (size_t)row0 * 512 + lane * 8;
#pragma unroll
    for (int r = 0; r < 8; r += 2) {
        const f32x4v a0 = __builtin_nontemporal_load((const f32x4v*)(rp + (size_t)r * 512));
        const f32x4v b0 = __builtin_nontemporal_load((const f32x4v*)(rp + (size_t)r * 512 + 4));
        const f32x4v a1 = __builtin_nontemporal_load((const f32x4v*)(rp + (size_t)(r + 1) * 512));
        const f32x4v b1 = __builtin_nontemporal_load((const f32x4v*)(rp + (size_t)(r + 1) * 512 + 4));
        float m0 = amax8(a0, b0);
        float m1 = amax8(a1, b1);
#pragma unroll
        for (int m = 1; m <= 32; m <<= 1) {        // interleaved dual reduce
            m0 = fmaxf(m0, __shfl_xor(m0, m, 64));
            m1 = fmaxf(m1, __shfl_xor(m1, m, 64));
        }
        const float inv0 = m0 > 0.f ? QMAX / m0 : 0.f;
        const float inv1 = m1 > 0.f ? QMAX / m1 : 0.f;
        if (lane == 0) {
            lscale[row0 + r]     = m0 > 0.f ? m0 * (1.0f / QMAX) : 1.0f;
            lscale[row0 + r + 1] = m1 > 0.f ? m1 * (1.0f / QMAX) : 1.0f;
        }
        i32x2 p0, p1;
        p0.x = (int)pack4(a0, inv0); p0.y = (int)pack4(b0, inv0);
        p1.x = (int)pack4(a1, inv1); p1.y = (int)pack4(b1, inv1);
        *(i32x2*)(op + (size_t)r * 512)       = p0;   // normal store: Aq wants L3 residency
        *(i32x2*)(op + (size_t)(r + 1) * 512) = p1;
    }
}

// ---- kernel 2: int8 GEMM, 256x128 tile, BK=128, 512 threads (8 waves 4x2),
// single-buffer 48KB LDS. __launch_bounds__(512,4): 128 regs/wave (fits
// acc 64 + half-frags 32 + addr; R10's (512,6) forced an 85-reg budget and
// spilled the accumulator to scratch -> 565MB WRITE). 2 blocks/CU = 16
// waves/CU of cross-block overlap (m114).
// XCD-aware swizzle: 4 n-tiles of each m-slab on one XCD (A re-reads hit L2).
// LDS XOR-swizzle via pre-swizzled GLOBAL source (m173; gload_lds dest linear).
__global__ __launch_bounds__(512, 4) void gemm_kernel(const int8_t* __restrict__ Aq,
                                                      const int8_t* __restrict__ Bt,
                                                      const float* __restrict__ lscale,
                                                      const float* __restrict__ rscale,
                                                      float* __restrict__ out) {
    __shared__ int8_t lds[49152];  // A [256][128] @0, B^T [128][128] @32768 (both swizzled)

    const int tid  = threadIdx.x;
    const int lane = tid & 63;
    const int wave = tid >> 6;      // 0..7
    const int wr   = wave >> 1;     // 0..3  (64-row band)
    const int wc   = wave & 1;      // 0..1  (64-col band)

    // 1024 blocks = 8 XCDs x 128; slab = xcd*32 + j/4, nc = j%4  (bijective)
    const int g   = blockIdx.x;
    const int xcd = g & 7;
    const int j   = g >> 3;
    const int m0  = (xcd * 32 + (j >> 2)) * 256;
    const int n0  = (j & 3) * 128;

    i32x4 acc[4][4];
#pragma unroll
    for (int i = 0; i < 4; ++i)
#pragma unroll
        for (int jj = 0; jj < 4; ++jj)
            acc[i][jj] = (i32x4){0, 0, 0, 0};

    const int lane15 = lane & 15;
    const int laneHi = lane >> 4;

#pragma unroll
    for (int kt = 0; kt < 512; kt += 128) {
        __syncthreads();   // previous step's frags consumed
        // stage A 32KB: 4 wave-uniform 1KB chunks per wave
#pragma unroll
        for (int c = 0; c < 4; ++c) {
            const int chunk = (c * 8 + wave) * 1024;
            const int d     = chunk + lane * 16;       // linear LDS dest byte
            const int row   = d >> 7;                  // A tile row 0..255
            const int srck  = (d & 127) ^ ((row & 7) << 4);
            const int8_t* srcA = Aq + (size_t)(m0 + row) * 512 + kt + srck;
            __builtin_amdgcn_global_load_lds((GVoid*)srcA, (LVoid*)(lds + chunk), 16, 0, 0);
        }
        // stage B 16KB: 2 chunks per wave
#pragma unroll
        for (int c = 0; c < 2; ++c) {
            const int chunk = (c * 8 + wave) * 1024;
            const int d     = chunk + lane * 16;
            const int row   = d >> 7;                  // B tile col 0..127
            const int srck  = (d & 127) ^ ((row & 7) << 4);
            const int8_t* srcB = Bt + (size_t)(n0 + row) * 512 + kt + srck;
            __builtin_amdgcn_global_load_lds((GVoid*)srcB, (LVoid*)(lds + 32768 + chunk), 16, 0, 0);
        }
        __syncthreads();   // staging complete (compiler drains vmcnt at barrier)

#pragma unroll
        for (int kk = 0; kk < 2; ++kk) {               // split so only half the frags are live
            const int kb = kk * 64 + laneHi * 16;
            i32x4 af[4], bf[4];
#pragma unroll
            for (int mi = 0; mi < 4; ++mi) {
                const int row = wr * 64 + mi * 16 + lane15;
                af[mi] = *(const i32x4*)(lds + row * 128 + (kb ^ ((row & 7) << 4)));
            }
#pragma unroll
            for (int ni = 0; ni < 4; ++ni) {
                const int col = wc * 64 + ni * 16 + lane15;
                bf[ni] = *(const i32x4*)(lds + 32768 + col * 128 + (kb ^ ((col & 7) << 4)));
            }
#pragma unroll
            for (int mi = 0; mi < 4; ++mi)
#pragma unroll
                for (int ni = 0; ni < 4; ++ni)
                    acc[mi][ni] = __builtin_amdgcn_mfma_i32_16x16x64_i8(
                        af[mi], bf[ni], acc[mi][ni], 0, 0, 0);
        }
    }

    // ---- epilogue: C/D layout col=lane&15, row=(lane>>4)*4+reg ----
    float rs[4];
#pragma unroll
    for (int ni = 0; ni < 4; ++ni)
        rs[ni] = rscale[n0 + wc * 64 + ni * 16 + lane15];
    const int rg = laneHi * 4;
#pragma unroll
    for (int mi = 0; mi < 4; ++mi) {
#pragma unroll
        for (int r = 0; r < 4; ++r) {
            const int grow = m0 + wr * 64 + mi * 16 + rg + r;
            const float ls = lscale[grow];
            float* op = out + (size_t)grow * 512 + n0 + wc * 64;
#pragma unroll
            for (int ni = 0; ni < 4; ++ni)
                op[ni * 16 + lane15] = (float)acc[mi][ni][r] * ls * rs[ni];
        }
    }
}

extern "C" void kernel_launch(void* const* d_in, const int* in_sizes, int n_in,
                              void* d_out, int out_size, void* d_ws, size_t ws_size,
                              hipStream_t stream) {
    const float* lhs = (const float*)d_in[0];   // [4,16384,512] f32
    const float* rhs = (const float*)d_in[1];   // [512,512] f32
    float* out = (float*)d_out;                 // [4,16384,512] f32

    // ws: Bt i8 [512][512] (256KB) | rscale f32[512] | lscale f32[65536] | Aq i8 [65536][512] (32MB)
    char* ws = (char*)d_ws;
    int8_t* Bt    = (int8_t*)ws;
    float* rscale = (float*)(ws + 262144);
    float* lscale = (float*)(ws + 266240);
    int8_t* Aq    = (int8_t*)(ws + 1048576);

    const int rows = in_sizes[0] / 512;         // 65536
    const int nLhs = rows / 32;                 // 2048

    quant_kernel<<<nLhs + 128, 256, 0, stream>>>(lhs, rhs, Aq, Bt, lscale, rscale, nLhs);
    gemm_kernel<<<(rows / 256) * 4, 512, 0, stream>>>(Aq, Bt, lscale, rscale, out);
}

// Round 12
// 77.563 us; speedup vs baseline: 2.6578x; 1.1052x over previous
//
#include <hip/hip_runtime.h>
#include <hip/hip_bf16.h>
#include <stdint.h>

#define QMAX 127.0f

typedef __attribute__((ext_vector_type(4))) int   i32x4;
typedef __attribute__((ext_vector_type(2))) int   i32x2;
typedef __attribute__((ext_vector_type(4))) float f32x4v;

typedef __attribute__((address_space(1))) const void GVoid;
typedef __attribute__((address_space(3))) void LVoid;

__device__ inline int quant_i(float x, float inv) {
    float q = rintf(x * inv);                 // inv = 127/absmax (one div per row)
    q = fminf(fmaxf(q, -QMAX), QMAX);
    return (int)q;                            // exact: q integral, |q|<=127
}

__device__ inline uint32_t pack4(f32x4v v, float inv) {
    return (uint32_t)(quant_i(v.x, inv) & 255)
         | ((uint32_t)(quant_i(v.y, inv) & 255) << 8)
         | ((uint32_t)(quant_i(v.z, inv) & 255) << 16)
         | ((uint32_t)(quant_i(v.w, inv) & 255) << 24);
}

__device__ inline float amax8(f32x4v a, f32x4v b) {
    return fmaxf(fmaxf(fmaxf(fabsf(a.x), fabsf(a.y)), fmaxf(fabsf(a.z), fabsf(a.w))),
                 fmaxf(fmaxf(fabsf(b.x), fabsf(b.y)), fmaxf(fabsf(b.z), fabsf(b.w))));
}

// ---- kernel 1: fused quantizer (single dispatch) ----
// blocks [0, nLhs): quantize 32 lhs rows each -> int8 Aq + lscale (NT loads: lhs dead after)
// blocks [nLhs, nLhs+128): wave w quantizes rhs column (b-nLhs)*4+w -> Bt int8 [F][K] + rscale
__global__ __launch_bounds__(256, 8) void quant_kernel(const float* __restrict__ lhs,
                                                       const float* __restrict__ rhs,
                                                       int8_t* __restrict__ Aq,
                                                       int8_t* __restrict__ Bt,
                                                       float* __restrict__ lscale,
                                                       float* __restrict__ rscale,
                                                       int nLhs) {
    const int lane = threadIdx.x & 63;
    const int wave = threadIdx.x >> 6;
    const int bid  = blockIdx.x;

    if (bid >= nLhs) {
        // ---- rhs path: one wave per column ----
        const int f = (bid - nLhs) * 4 + wave;
        float v[8];
        float amax = 0.f;
#pragma unroll
        for (int i = 0; i < 8; ++i) {
            v[i] = rhs[(size_t)(lane + 64 * i) * 512 + f];
            amax = fmaxf(amax, fabsf(v[i]));
        }
#pragma unroll
        for (int m = 1; m <= 32; m <<= 1)
            amax = fmaxf(amax, __shfl_xor(amax, m, 64));
        const float inv = amax > 0.f ? QMAX / amax : 0.f;
        if (lane == 0) rscale[f] = amax > 0.f ? amax * (1.0f / QMAX) : 1.0f;
#pragma unroll
        for (int i = 0; i < 8; ++i)
            Bt[(size_t)f * 512 + lane + 64 * i] = (int8_t)quant_i(v[i], inv);
        return;
    }

    // ---- lhs path: this wave owns 8 rows ----
    const int row0 = bid * 32 + wave * 8;
    const float* rp = lhs + (size_t)row0 * 512 + lane * 8;
    int8_t* op = Aq + (size_t)row0 * 512 + lane * 8;
#pragma unroll
    for (int r = 0; r < 8; r += 2) {
        const f32x4v a0 = __builtin_nontemporal_load((const f32x4v*)(rp + (size_t)r * 512));
        const f32x4v b0 = __builtin_nontemporal_load((const f32x4v*)(rp + (size_t)r * 512 + 4));
        const f32x4v a1 = __builtin_nontemporal_load((const f32x4v*)(rp + (size_t)(r + 1) * 512));
        const f32x4v b1 = __builtin_nontemporal_load((const f32x4v*)(rp + (size_t)(r + 1) * 512 + 4));
        float m0 = amax8(a0, b0);
        float m1 = amax8(a1, b1);
#pragma unroll
        for (int m = 1; m <= 32; m <<= 1) {        // interleaved dual reduce
            m0 = fmaxf(m0, __shfl_xor(m0, m, 64));
            m1 = fmaxf(m1, __shfl_xor(m1, m, 64));
        }
        const float inv0 = m0 > 0.f ? QMAX / m0 : 0.f;
        const float inv1 = m1 > 0.f ? QMAX / m1 : 0.f;
        if (lane == 0) {
            lscale[row0 + r]     = m0 > 0.f ? m0 * (1.0f / QMAX) : 1.0f;
            lscale[row0 + r + 1] = m1 > 0.f ? m1 * (1.0f / QMAX) : 1.0f;
        }
        i32x2 p0, p1;
        p0.x = (int)pack4(a0, inv0); p0.y = (int)pack4(b0, inv0);
        p1.x = (int)pack4(a1, inv1); p1.y = (int)pack4(b1, inv1);
        *(i32x2*)(op + (size_t)r * 512)       = p0;   // normal store: Aq wants L3 residency
        *(i32x2*)(op + (size_t)(r + 1) * 512) = p1;
    }
}

// ---- kernel 2: int8 GEMM, m97 skeleton (R9 verbatim except min-waves):
// 128x128 tile, BK=128, single-buffer 32KB LDS, __launch_bounds__(256,4)
// -> 4 independent blocks/CU = 16 waves/CU in 4 barrier domains (m114:
// cross-block overlap is the engine; R11 showed big blocks with wide
// barriers lose to many small blocks). Unified reg budget 128 fits
// arch ~40 + acc 64, no spill.
// XCD-aware swizzle: the 4 n-tiles of each m-slab run on the SAME XCD so the
// A-slab is fetched from HBM once and re-read from that XCD's L2.
// LDS XOR-swizzle via pre-swizzled GLOBAL source (m173; gload_lds dest linear).
__global__ __launch_bounds__(256, 4) void gemm_kernel(const int8_t* __restrict__ Aq,
                                                      const int8_t* __restrict__ Bt,
                                                      const float* __restrict__ lscale,
                                                      const float* __restrict__ rscale,
                                                      float* __restrict__ out) {
    __shared__ int8_t lds[32768];  // A [128][128] @0, B^T [128][128] @16384 (both swizzled)

    const int tid  = threadIdx.x;
    const int lane = tid & 63;
    const int wave = tid >> 6;
    const int wr   = wave >> 1;
    const int wc   = wave & 1;

    // 2048 blocks = 8 XCDs x 256; slab = xcd*64 + j/4, nc = j%4  (bijective)
    const int g   = blockIdx.x;
    const int xcd = g & 7;
    const int j   = g >> 3;
    const int m0  = (xcd * 64 + (j >> 2)) * 128;
    const int n0  = (j & 3) * 128;

    i32x4 acc[4][4];
#pragma unroll
    for (int i = 0; i < 4; ++i)
#pragma unroll
        for (int jj = 0; jj < 4; ++jj)
            acc[i][jj] = (i32x4){0, 0, 0, 0};

    const int lane15 = lane & 15;
    const int laneHi = lane >> 4;

#pragma unroll
    for (int kt = 0; kt < 512; kt += 128) {
        __syncthreads();   // previous step's frags consumed
#pragma unroll
        for (int c = 0; c < 4; ++c) {
            const int chunk = (c * 4 + wave) * 1024;   // wave-uniform 1KB chunk
            const int d     = chunk + lane * 16;       // linear LDS dest byte
            const int row   = d >> 7;                  // tile row (A) / col (B)
            const int koff  = d & 127;                 // 16-aligned
            const int srck  = koff ^ ((row & 7) << 4); // pre-swizzled source k
            const int8_t* srcA = Aq + (size_t)(m0 + row) * 512 + kt + srck;
            __builtin_amdgcn_global_load_lds((GVoid*)srcA, (LVoid*)(lds + chunk), 16, 0, 0);
            const int8_t* srcB = Bt + (size_t)(n0 + row) * 512 + kt + srck;
            __builtin_amdgcn_global_load_lds((GVoid*)srcB, (LVoid*)(lds + 16384 + chunk), 16, 0, 0);
        }
        __syncthreads();   // staging complete (compiler drains vmcnt at barrier)

        i32x4 af[4][2], bf[4][2];
#pragma unroll
        for (int mi = 0; mi < 4; ++mi) {
            const int row = wr * 64 + mi * 16 + lane15;
            const int sw  = (row & 7) << 4;
#pragma unroll
            for (int kk = 0; kk < 2; ++kk) {
                const int kb = kk * 64 + laneHi * 16;
                af[mi][kk] = *(const i32x4*)(lds + row * 128 + (kb ^ sw));
            }
        }
#pragma unroll
        for (int ni = 0; ni < 4; ++ni) {
            const int col = wc * 64 + ni * 16 + lane15;
            const int sw  = (col & 7) << 4;
#pragma unroll
            for (int kk = 0; kk < 2; ++kk) {
                const int kb = kk * 64 + laneHi * 16;
                bf[ni][kk] = *(const i32x4*)(lds + 16384 + col * 128 + (kb ^ sw));
            }
        }
#pragma unroll
        for (int kk = 0; kk < 2; ++kk)
#pragma unroll
            for (int mi = 0; mi < 4; ++mi)
#pragma unroll
                for (int ni = 0; ni < 4; ++ni)
                    acc[mi][ni] = __builtin_amdgcn_mfma_i32_16x16x64_i8(
                        af[mi][kk], bf[ni][kk], acc[mi][ni], 0, 0, 0);
    }

    // ---- epilogue: C/D layout col=lane&15, row=(lane>>4)*4+reg ----
    float rs[4];
#pragma unroll
    for (int ni = 0; ni < 4; ++ni)
        rs[ni] = rscale[n0 + wc * 64 + ni * 16 + lane15];
    const int rg = laneHi * 4;
#pragma unroll
    for (int mi = 0; mi < 4; ++mi) {
#pragma unroll
        for (int r = 0; r < 4; ++r) {
            const int grow = m0 + wr * 64 + mi * 16 + rg + r;
            const float ls = lscale[grow];
            float* op = out + (size_t)grow * 512 + n0 + wc * 64;
#pragma unroll
            for (int ni = 0; ni < 4; ++ni)
                op[ni * 16 + lane15] = (float)acc[mi][ni][r] * ls * rs[ni];
        }
    }
}

extern "C" void kernel_launch(void* const* d_in, const int* in_sizes, int n_in,
                              void* d_out, int out_size, void* d_ws, size_t ws_size,
                              hipStream_t stream) {
    const float* lhs = (const float*)d_in[0];   // [4,16384,512] f32
    const float* rhs = (const float*)d_in[1];   // [512,512] f32
    float* out = (float*)d_out;                 // [4,16384,512] f32

    // ws: Bt i8 [512][512] (256KB) | rscale f32[512] | lscale f32[65536] | Aq i8 [65536][512] (32MB)
    char* ws = (char*)d_ws;
    int8_t* Bt    = (int8_t*)ws;
    float* rscale = (float*)(ws + 262144);
    float* lscale = (float*)(ws + 266240);
    int8_t* Aq    = (int8_t*)(ws + 1048576);

    const int rows = in_sizes[0] / 512;         // 65536
    const int nLhs = rows / 32;                 // 2048

    quant_kernel<<<nLhs + 128, 256, 0, stream>>>(lhs, rhs, Aq, Bt, lscale, rscale, nLhs);
    gemm_kernel<<<(rows / 128) * 4, 256, 0, stream>>>(Aq, Bt, lscale, rscale, out);
}

// Round 13
// 70.734 us; speedup vs baseline: 2.9144x; 1.0966x over previous
//
#include <hip/hip_runtime.h>
#include <hip/hip_bf16.h>
#include <stdint.h>

#define QMAX 127.0f

typedef __attribute__((ext_vector_type(4))) int   i32x4;
typedef __attribute__((ext_vector_type(2))) int   i32x2;
typedef __attribute__((ext_vector_type(4))) float f32x4v;

typedef __attribute__((address_space(1))) const void GVoid;
typedef __attribute__((address_space(3))) void LVoid;

__device__ inline int quant_i(float x, float inv) {
    float q = rintf(x * inv);                 // inv = 127/absmax (one div per row)
    q = fminf(fmaxf(q, -QMAX), QMAX);
    return (int)q;                            // exact: q integral, |q|<=127
}

__device__ inline uint32_t pack4(f32x4v v, float inv) {
    return (uint32_t)(quant_i(v.x, inv) & 255)
         | ((uint32_t)(quant_i(v.y, inv) & 255) << 8)
         | ((uint32_t)(quant_i(v.z, inv) & 255) << 16)
         | ((uint32_t)(quant_i(v.w, inv) & 255) << 24);
}

__device__ inline float amax8(f32x4v a, f32x4v b) {
    return fmaxf(fmaxf(fmaxf(fabsf(a.x), fabsf(a.y)), fmaxf(fabsf(a.z), fabsf(a.w))),
                 fmaxf(fmaxf(fabsf(b.x), fabsf(b.y)), fmaxf(fabsf(b.z), fabsf(b.w))));
}

// ---- kernel 1: fused quantizer (single dispatch) ----
// blocks [0, nLhs): quantize 32 lhs rows each -> int8 Aq + lscale (NT loads: lhs dead after)
// blocks [nLhs, nLhs+128): wave w quantizes rhs column (b-nLhs)*4+w -> Bt int8 [F][K] + rscale
__global__ __launch_bounds__(256, 8) void quant_kernel(const float* __restrict__ lhs,
                                                       const float* __restrict__ rhs,
                                                       int8_t* __restrict__ Aq,
                                                       int8_t* __restrict__ Bt,
                                                       float* __restrict__ lscale,
                                                       float* __restrict__ rscale,
                                                       int nLhs) {
    const int lane = threadIdx.x & 63;
    const int wave = threadIdx.x >> 6;
    const int bid  = blockIdx.x;

    if (bid >= nLhs) {
        // ---- rhs path: one wave per column ----
        const int f = (bid - nLhs) * 4 + wave;
        float v[8];
        float amax = 0.f;
#pragma unroll
        for (int i = 0; i < 8; ++i) {
            v[i] = rhs[(size_t)(lane + 64 * i) * 512 + f];
            amax = fmaxf(amax, fabsf(v[i]));
        }
#pragma unroll
        for (int m = 1; m <= 32; m <<= 1)
            amax = fmaxf(amax, __shfl_xor(amax, m, 64));
        const float inv = amax > 0.f ? QMAX / amax : 0.f;
        if (lane == 0) rscale[f] = amax > 0.f ? amax * (1.0f / QMAX) : 1.0f;
#pragma unroll
        for (int i = 0; i < 8; ++i)
            Bt[(size_t)f * 512 + lane + 64 * i] = (int8_t)quant_i(v[i], inv);
        return;
    }

    // ---- lhs path: this wave owns 8 rows ----
    const int row0 = bid * 32 + wave * 8;
    const float* rp = lhs + (size_t)row0 * 512 + lane * 8;
    int8_t* op = Aq + (size_t)row0 * 512 + lane * 8;
#pragma unroll
    for (int r = 0; r < 8; r += 2) {
        const f32x4v a0 = __builtin_nontemporal_load((const f32x4v*)(rp + (size_t)r * 512));
        const f32x4v b0 = __builtin_nontemporal_load((const f32x4v*)(rp + (size_t)r * 512 + 4));
        const f32x4v a1 = __builtin_nontemporal_load((const f32x4v*)(rp + (size_t)(r + 1) * 512));
        const f32x4v b1 = __builtin_nontemporal_load((const f32x4v*)(rp + (size_t)(r + 1) * 512 + 4));
        float m0 = amax8(a0, b0);
        float m1 = amax8(a1, b1);
#pragma unroll
        for (int m = 1; m <= 32; m <<= 1) {        // interleaved dual reduce
            m0 = fmaxf(m0, __shfl_xor(m0, m, 64));
            m1 = fmaxf(m1, __shfl_xor(m1, m, 64));
        }
        const float inv0 = m0 > 0.f ? QMAX / m0 : 0.f;
        const float inv1 = m1 > 0.f ? QMAX / m1 : 0.f;
        if (lane == 0) {
            lscale[row0 + r]     = m0 > 0.f ? m0 * (1.0f / QMAX) : 1.0f;
            lscale[row0 + r + 1] = m1 > 0.f ? m1 * (1.0f / QMAX) : 1.0f;
        }
        i32x2 p0, p1;
        p0.x = (int)pack4(a0, inv0); p0.y = (int)pack4(b0, inv0);
        p1.x = (int)pack4(a1, inv1); p1.y = (int)pack4(b1, inv1);
        *(i32x2*)(op + (size_t)r * 512)       = p0;   // normal store: Aq wants L3 residency
        *(i32x2*)(op + (size_t)(r + 1) * 512) = p1;
    }
}

// ---- kernel 2: int8 GEMM, 128x128 tile, BK=128, double-buffered LDS with
// COUNTED vmcnt (T4): tile t+1's 8 gload_lds stay in flight across the
// barrier and retire under tile t's MFMA phase. R8's failed dbuf used
// __syncthreads (vmcnt(0) drain) -- the prefetch was drained before use.
// Raw s_barrier + "s_waitcnt vmcnt(8)" keeps it live. Buffer reuse guarded
// by the end-of-iteration barrier (all waves' ds_reads retired by MFMA
// data-dependence before reaching it).
// XCD-aware swizzle: 4 n-tiles of each m-slab on one XCD (A re-reads hit L2).
// LDS XOR-swizzle via pre-swizzled GLOBAL source (m173; gload_lds dest linear).
__global__ __launch_bounds__(256, 2) void gemm_kernel(const int8_t* __restrict__ Aq,
                                                      const int8_t* __restrict__ Bt,
                                                      const float* __restrict__ lscale,
                                                      const float* __restrict__ rscale,
                                                      float* __restrict__ out) {
    __shared__ int8_t lds[65536];  // 2 x { A [128][128] @0, B^T [128][128] @16384 }

    const int tid  = threadIdx.x;
    const int lane = tid & 63;
    const int wave = tid >> 6;
    const int wr   = wave >> 1;
    const int wc   = wave & 1;

    // 2048 blocks = 8 XCDs x 256; slab = xcd*64 + j/4, nc = j%4  (bijective)
    const int g   = blockIdx.x;
    const int xcd = g & 7;
    const int j   = g >> 3;
    const int m0  = (xcd * 64 + (j >> 2)) * 128;
    const int n0  = (j & 3) * 128;

    i32x4 acc[4][4];
#pragma unroll
    for (int i = 0; i < 4; ++i)
#pragma unroll
        for (int jj = 0; jj < 4; ++jj)
            acc[i][jj] = (i32x4){0, 0, 0, 0};

    const int lane15 = lane & 15;
    const int laneHi = lane >> 4;

#define STAGE(KT, BUF)                                                              \
    {                                                                               \
        _Pragma("unroll")                                                           \
        for (int c = 0; c < 4; ++c) {                                               \
            const int chunk = (c * 4 + wave) * 1024;                                \
            const int d     = chunk + lane * 16;                                    \
            const int row   = d >> 7;                                               \
            const int srck  = (d & 127) ^ ((row & 7) << 4);                         \
            const int8_t* sA = Aq + (size_t)(m0 + row) * 512 + (KT) + srck;         \
            __builtin_amdgcn_global_load_lds((GVoid*)sA, (LVoid*)(lds + (BUF) + chunk), 16, 0, 0); \
            const int8_t* sB = Bt + (size_t)(n0 + row) * 512 + (KT) + srck;         \
            __builtin_amdgcn_global_load_lds((GVoid*)sB, (LVoid*)(lds + (BUF) + 16384 + chunk), 16, 0, 0); \
        }                                                                           \
    }

    STAGE(0, 0)                                 // 8 loads in flight (tile 0)

#pragma unroll
    for (int t = 0; t < 4; ++t) {
        const int buf = (t & 1) * 32768;
        if (t < 3) {
            STAGE((t + 1) * 128, ((t + 1) & 1) * 32768)   // +8 loads (tile t+1)
            asm volatile("s_waitcnt vmcnt(8)" ::: "memory");  // tile t landed; t+1 in flight
        } else {
            asm volatile("s_waitcnt vmcnt(0)" ::: "memory");  // last tile landed
        }
        __builtin_amdgcn_s_barrier();           // all waves see tile t in LDS
        __builtin_amdgcn_sched_barrier(0);      // pin: no ds_read hoisted above

        i32x4 af[4][2], bf[4][2];
#pragma unroll
        for (int mi = 0; mi < 4; ++mi) {
            const int row = wr * 64 + mi * 16 + lane15;
            const int sw  = (row & 7) << 4;
#pragma unroll
            for (int kk = 0; kk < 2; ++kk) {
                const int kb = kk * 64 + laneHi * 16;
                af[mi][kk] = *(const i32x4*)(lds + buf + row * 128 + (kb ^ sw));
            }
        }
#pragma unroll
        for (int ni = 0; ni < 4; ++ni) {
            const int col = wc * 64 + ni * 16 + lane15;
            const int sw  = (col & 7) << 4;
#pragma unroll
            for (int kk = 0; kk < 2; ++kk) {
                const int kb = kk * 64 + laneHi * 16;
                bf[ni][kk] = *(const i32x4*)(lds + buf + 16384 + col * 128 + (kb ^ sw));
            }
        }
#pragma unroll
        for (int kk = 0; kk < 2; ++kk)
#pragma unroll
            for (int mi = 0; mi < 4; ++mi)
#pragma unroll
                for (int ni = 0; ni < 4; ++ni)
                    acc[mi][ni] = __builtin_amdgcn_mfma_i32_16x16x64_i8(
                        af[mi][kk], bf[ni][kk], acc[mi][ni], 0, 0, 0);

        if (t < 3) __builtin_amdgcn_s_barrier();   // all waves done reading buf
                                                   // (ds_reads retired via MFMA deps)
    }
#undef STAGE

    // ---- epilogue: C/D layout col=lane&15, row=(lane>>4)*4+reg ----
    float rs[4];
#pragma unroll
    for (int ni = 0; ni < 4; ++ni)
        rs[ni] = rscale[n0 + wc * 64 + ni * 16 + lane15];
    const int rg = laneHi * 4;
#pragma unroll
    for (int mi = 0; mi < 4; ++mi) {
#pragma unroll
        for (int r = 0; r < 4; ++r) {
            const int grow = m0 + wr * 64 + mi * 16 + rg + r;
            const float ls = lscale[grow];
            float* op = out + (size_t)grow * 512 + n0 + wc * 64;
#pragma unroll
            for (int ni = 0; ni < 4; ++ni)
                op[ni * 16 + lane15] = (float)acc[mi][ni][r] * ls * rs[ni];
        }
    }
}

extern "C" void kernel_launch(void* const* d_in, const int* in_sizes, int n_in,
                              void* d_out, int out_size, void* d_ws, size_t ws_size,
                              hipStream_t stream) {
    const float* lhs = (const float*)d_in[0];   // [4,16384,512] f32
    const float* rhs = (const float*)d_in[1];   // [512,512] f32
    float* out = (float*)d_out;                 // [4,16384,512] f32

    // ws: Bt i8 [512][512] (256KB) | rscale f32[512] | lscale f32[65536] | Aq i8 [65536][512] (32MB)
    char* ws = (char*)d_ws;
    int8_t* Bt    = (int8_t*)ws;
    float* rscale = (float*)(ws + 262144);
    float* lscale = (float*)(ws + 266240);
    int8_t* Aq    = (int8_t*)(ws + 1048576);

    const int rows = in_sizes[0] / 512;         // 65536
    const int nLhs = rows / 32;                 // 2048

    quant_kernel<<<nLhs + 128, 256, 0, stream>>>(lhs, rhs, Aq, Bt, lscale, rscale, nLhs);
    gemm_kernel<<<(rows / 128) * 4, 256, 0, stream>>>(Aq, Bt, lscale, rscale, out);
}